// Round 1
// baseline (168.330 us; speedup 1.0000x reference)
//
#include <hip/hip_runtime.h>
#include <math.h>

#define EPSF 1e-15f

// ---------------------------------------------------------------------------
// Problem: HyperGRU cell, B=H=IN=Cc=256, c=1, fp32.
// Key algebra: in _mlr, q[c,b] = tanh(r[b]*|z_c|) * zhat_c and a_unit = zhat_c,
// so px = (-q) (+) x_b lies in span{zhat_c, x_b}; dot & |px|^2 are closed-form
// scalars of d = <zhat_c, x_b>, x2 = |x_b|^2, t = tanh(r[b]*|z_c|).
// => whole _fc = one 256^3 matmul Z*X^T + elementwise transcendentals.
// Dead code in reference (Wh/Uh fc's, r_point_h) is skipped.
//
// ws layout (floats):
//   W0..W3 [b][c] 256x256 at mat*65536            (w = sinh(logits), pre-scale)
//   Spart  at 262144 + mat*2048 + ctile*256 + b   (partial sums of w^2 over c)
// ---------------------------------------------------------------------------

__device__ __forceinline__ float wredsum(float v){
    #pragma unroll
    for (int o = 32; o > 0; o >>= 1) v += __shfl_xor(v, o);
    return v;
}
__device__ __forceinline__ void wredsum3(float& a, float& b, float& c){
    #pragma unroll
    for (int o = 32; o > 0; o >>= 1){
        a += __shfl_xor(a, o);
        b += __shfl_xor(b, o);
        c += __shfl_xor(c, o);
    }
}
__device__ __forceinline__ float artanh_f(float x){
    return 0.5f * logf((1.f + x) / (1.f - x));
}

// Given M = <Z_row_c, X_row_b> (unnormalized), nzc=max(|Z_c|,eps),
// nac = |a_c| = nzc/cosh(r[c])^2, rb = r[b], x2b = |x_b|^2:
// returns w[b,c] = sinh(logits[b,c]) of the reference _fc (before scale).
__device__ __forceinline__ float fc_elem(float M, float nzc, float nac, float rb, float x2b){
    const float maxn = 1.0f - 4e-3f;
    float d = M / nzc;                       // <zhat_c, x_b>
    float tq = tanhf(rb * nzc);              // q = tq*zhat  (expmap0), |q|=|tq|
    if (fabsf(tq) > maxn) tq = copysignf(maxn, tq);    // _project(q)
    float A   = 1.f - 2.f*tq*d + x2b;        // 1 + 2<-q,x> + |x|^2
    float den = 1.f - 2.f*tq*d + tq*tq*x2b;  // 1 + 2<-q,x> + |q|^2 |x|^2
    den = fmaxf(den, EPSF);
    float alpha = -tq * A / den;             // px = alpha*zhat + beta*x
    float beta  = (1.f - tq*tq) / den;
    float dot  = alpha + beta * d;           // <px, zhat>
    float pxn2 = alpha*alpha + 2.f*alpha*beta*d + beta*beta*x2b;
    pxn2 = fmaxf(pxn2, 0.f);
    float n = fmaxf(sqrtf(pxn2), EPSF);
    if (n > maxn){                           // _project(px)
        float s = maxn / n;
        dot *= s;
        pxn2 = maxn * maxn;
    }
    float lam = 2.f / (1.f - pxn2);
    float logit = 2.f * nac * asinhf(dot * lam);
    return sinhf(logit);
}

// One block = one 32x32 tile of one of the 4 fc matmuls M[c,b] = <Z_c, X_b>.
// Fuses: row norms (nz, na, x2), fc elementwise, transposed store W[b][c],
// and per-tile partial sums Spart[b] = sum_{c in tile} w[b,c]^2.
__global__ __launch_bounds__(256) void fc_kernel(
    const float* __restrict__ hidden, const float* __restrict__ hyp_x,
    const float* __restrict__ Wz_z, const float* __restrict__ Uz_z,
    const float* __restrict__ Wr_z, const float* __restrict__ Ur_z,
    const float* __restrict__ Wz_r, const float* __restrict__ Uz_r,
    const float* __restrict__ Wr_r, const float* __restrict__ Ur_r,
    float* __restrict__ ws)
{
    __shared__ float As[32][132];   // pad 132: row stride 4 banks -> <=2-way (free)
    __shared__ float Bs[32][132];
    __shared__ float nz_s[32], na_s[32], x2_s[32], Sred[32];

    const int bid   = blockIdx.x;
    const int mat   = bid >> 6;         // 0:Wz 1:Uz 2:Wr 3:Ur
    const int tile  = bid & 63;
    const int ctile = tile >> 3;
    const int cbase = ctile * 32;
    const int bbase = (tile & 7) * 32;

    const float* Z  = (mat==0) ? Wz_z : (mat==1) ? Uz_z : (mat==2) ? Wr_z : Ur_z;
    const float* Rv = (mat==0) ? Wz_r : (mat==1) ? Uz_r : (mat==2) ? Wr_r : Ur_r;
    const float* X  = (mat==0 || mat==2) ? hidden : hyp_x;

    const int t  = threadIdx.x;
    const int tc = t >> 4, tb = t & 15;

    float acc00 = 0.f, acc01 = 0.f, acc10 = 0.f, acc11 = 0.f;
    float sa = 0.f, sb = 0.f;           // norm^2 partials (8 threads per row)

    for (int half = 0; half < 2; ++half){
        #pragma unroll
        for (int q = 0; q < 4; ++q){
            int f   = q*256 + t;        // 0..1023 float4 slots
            int row = f >> 5;
            int col = (f & 31) * 4;
            *(float4*)&As[row][col] = *(const float4*)(Z + (cbase+row)*256 + half*128 + col);
            *(float4*)&Bs[row][col] = *(const float4*)(X + (bbase+row)*256 + half*128 + col);
        }
        __syncthreads();

        {   // accumulate row-norm partials from staged tiles
            int r = t >> 3, seg = t & 7;
            #pragma unroll
            for (int q = 0; q < 4; ++q){
                float4 a = *(const float4*)&As[r][seg*16 + q*4];
                float4 b = *(const float4*)&Bs[r][seg*16 + q*4];
                sa += a.x*a.x + a.y*a.y + a.z*a.z + a.w*a.w;
                sb += b.x*b.x + b.y*b.y + b.z*b.z + b.w*b.w;
            }
        }

        for (int k = 0; k < 128; k += 4){
            float4 a0 = *(const float4*)&As[tc][k];
            float4 a1 = *(const float4*)&As[tc+16][k];
            float4 b0 = *(const float4*)&Bs[tb][k];
            float4 b1 = *(const float4*)&Bs[tb+16][k];
            acc00 += a0.x*b0.x + a0.y*b0.y + a0.z*b0.z + a0.w*b0.w;
            acc01 += a0.x*b1.x + a0.y*b1.y + a0.z*b1.z + a0.w*b1.w;
            acc10 += a1.x*b0.x + a1.y*b0.y + a1.z*b0.z + a1.w*b0.w;
            acc11 += a1.x*b1.x + a1.y*b1.y + a1.z*b1.z + a1.w*b1.w;
        }
        __syncthreads();
    }

    // finish row norms (reduce the 8 segments; lanes r*8+seg are wave-contiguous)
    sa += __shfl_xor(sa, 1); sb += __shfl_xor(sb, 1);
    sa += __shfl_xor(sa, 2); sb += __shfl_xor(sb, 2);
    sa += __shfl_xor(sa, 4); sb += __shfl_xor(sb, 4);
    if ((t & 7) == 0){
        int r = t >> 3;
        float nzv = fmaxf(sqrtf(sa), EPSF);
        nz_s[r] = nzv;
        float ch = coshf(Rv[cbase + r]);
        na_s[r] = nzv / (ch*ch);
        x2_s[r] = sb;
    }
    if (t < 32) Sred[t] = 0.f;
    __syncthreads();

    const int c0 = cbase + tc, c1 = cbase + tc + 16;
    const int b0 = bbase + tb, b1 = bbase + tb + 16;
    float nz0 = nz_s[tc],   nz1 = nz_s[tc+16];
    float na0 = na_s[tc],   na1 = na_s[tc+16];
    float x20 = x2_s[tb],   x21 = x2_s[tb+16];
    float r0  = Rv[b0],     r1  = Rv[b1];

    float w00 = fc_elem(acc00, nz0, na0, r0, x20);   // -> W[b0][c0]
    float w01 = fc_elem(acc01, nz0, na0, r1, x21);   // -> W[b1][c0]
    float w10 = fc_elem(acc10, nz1, na1, r0, x20);   // -> W[b0][c1]
    float w11 = fc_elem(acc11, nz1, na1, r1, x21);   // -> W[b1][c1]

    float* Wout = ws + mat * 65536;
    Wout[b0*256 + c0] = w00;
    Wout[b1*256 + c0] = w01;
    Wout[b0*256 + c1] = w10;
    Wout[b1*256 + c1] = w11;

    atomicAdd(&Sred[tb],      w00*w00 + w10*w10);
    atomicAdd(&Sred[tb+16],   w01*w01 + w11*w11);
    __syncthreads();
    if (t < 32) ws[262144 + mat*2048 + ctile*256 + bbase + t] = Sred[t];
}

// wave-per-row Mobius add with projection; returns final norm (>= EPSF)
__device__ __forceinline__ float mobius_add4(const float x[4], const float y[4], float res[4]){
    float x2 = 0.f, y2 = 0.f, xy = 0.f;
    #pragma unroll
    for (int k = 0; k < 4; ++k){ x2 += x[k]*x[k]; y2 += y[k]*y[k]; xy += x[k]*y[k]; }
    wredsum3(x2, y2, xy);
    float cA  = 1.f + 2.f*xy + y2;
    float cB  = 1.f - x2;
    float den = fmaxf(1.f + 2.f*xy + x2*y2, EPSF);
    float n2  = 0.f;
    #pragma unroll
    for (int k = 0; k < 4; ++k){ res[k] = (cA*x[k] + cB*y[k]) / den; n2 += res[k]*res[k]; }
    n2 = wredsum(n2);
    float n = fmaxf(sqrtf(n2), EPSF);
    const float maxn = 1.0f - 4e-3f;
    if (n > maxn){
        float s = maxn / n;
        #pragma unroll
        for (int k = 0; k < 4; ++k) res[k] *= s;
        n = maxn;
    }
    return n;
}

// dst[k] = (sqrt(S_m[c]) + 1) * W_m[b][c]   (the _fc scale, indexed by column c)
__device__ __forceinline__ void load_G(const float* __restrict__ ws, int mat, int b, int c4, float dst[4]){
    const float* Wm = ws + mat*65536;
    float4 g = *(const float4*)(Wm + b*256 + c4);
    const float* Sp = ws + 262144 + mat*2048;
    float s0 = 0.f, s1 = 0.f, s2 = 0.f, s3 = 0.f;
    #pragma unroll
    for (int ct = 0; ct < 8; ++ct){
        float4 sp = *(const float4*)(Sp + ct*256 + c4);
        s0 += sp.x; s1 += sp.y; s2 += sp.z; s3 += sp.w;
    }
    dst[0] = (sqrtf(s0) + 1.f) * g.x;
    dst[1] = (sqrtf(s1) + 1.f) * g.y;
    dst[2] = (sqrtf(s2) + 1.f) * g.z;
    dst[3] = (sqrtf(s3) + 1.f) * g.w;
}

// One wave per output row b: the whole Mobius/logmap/sigmoid/pw-mul chain.
__global__ __launch_bounds__(256) void cell_kernel(
    const float* __restrict__ hidden,
    const float* __restrict__ b_z, const float* __restrict__ b_r, const float* __restrict__ b_h,
    const float* __restrict__ ws, float* __restrict__ out)
{
    const int b    = blockIdx.x * 4 + (threadIdx.x >> 6);
    const int lane = threadIdx.x & 63;
    const int c4   = lane * 4;
    const float maxn = 1.0f - 4e-3f;

    float h[4], u[4], v[4], t1[4], pre[4], zv[4], rv[4], ht[4], mh[4], tmp[4], pw[4];

    { float4 hv = *(const float4*)(hidden + b*256 + c4);
      h[0]=hv.x; h[1]=hv.y; h[2]=hv.z; h[3]=hv.w; }

    // ---- z gate: sigmoid(logmap0( (G(h,Wz) (+) G(x,Uz)) (+) b_z )) ----
    load_G(ws, 0, b, c4, u);
    load_G(ws, 1, b, c4, v);
    mobius_add4(u, v, t1);
    { float4 bb = *(const float4*)(b_z + c4); tmp[0]=bb.x; tmp[1]=bb.y; tmp[2]=bb.z; tmp[3]=bb.w; }
    float n  = mobius_add4(t1, tmp, pre);
    float tt = artanh_f(fminf(n, 1.f - 1e-7f));
    float sc = tt / n;
    #pragma unroll
    for (int k = 0; k < 4; ++k) zv[k] = 1.f / (1.f + expf(-pre[k]*sc));

    // ---- r gate ----
    load_G(ws, 2, b, c4, u);
    load_G(ws, 3, b, c4, v);
    mobius_add4(u, v, t1);
    { float4 bb = *(const float4*)(b_r + c4); tmp[0]=bb.x; tmp[1]=bb.y; tmp[2]=bb.z; tmp[3]=bb.w; }
    n  = mobius_add4(t1, tmp, pre);
    tt = artanh_f(fminf(n, 1.f - 1e-7f));
    sc = tt / n;
    #pragma unroll
    for (int k = 0; k < 4; ++k) rv[k] = 1.f / (1.f + expf(-pre[k]*sc));

    // ---- h_tilde = r (+) b_h ----
    { float4 bb = *(const float4*)(b_h + c4); tmp[0]=bb.x; tmp[1]=bb.y; tmp[2]=bb.z; tmp[3]=bb.w; }
    mobius_add4(rv, tmp, ht);

    // ---- mh = (-hidden) (+) h_tilde ----
    #pragma unroll
    for (int k = 0; k < 4; ++k) tmp[k] = -h[k];
    mobius_add4(tmp, ht, mh);

    // ---- pw = mobius_pointwise_mul(mh, z) ----
    float xn2 = 0.f, wxn2 = 0.f, dum = 0.f;
    #pragma unroll
    for (int k = 0; k < 4; ++k){ tmp[k] = mh[k]*zv[k]; xn2 += zv[k]*zv[k]; wxn2 += tmp[k]*tmp[k]; }
    wredsum3(xn2, wxn2, dum);
    float xn  = fmaxf(sqrtf(xn2),  EPSF);
    float wxn = fmaxf(sqrtf(wxn2), EPSF);
    float ttp = artanh_f(fminf(xn, 1.f - 1e-7f));
    float th  = tanhf(wxn / xn * ttp);
    float coef = th / wxn;                       // |pw| = th analytically
    if (th > maxn) coef *= maxn / th;            // _project(pw)
    #pragma unroll
    for (int k = 0; k < 4; ++k) pw[k] = coef * tmp[k];

    // ---- out = hidden (+) pw ----
    mobius_add4(h, pw, tmp);
    float4 o; o.x = tmp[0]; o.y = tmp[1]; o.z = tmp[2]; o.w = tmp[3];
    *(float4*)(out + b*256 + c4) = o;
}

extern "C" void kernel_launch(void* const* d_in, const int* in_sizes, int n_in,
                              void* d_out, int out_size, void* d_ws, size_t ws_size,
                              hipStream_t stream) {
    (void)in_sizes; (void)n_in; (void)out_size; (void)ws_size;
    const float* hyp_x  = (const float*)d_in[0];
    const float* hidden = (const float*)d_in[1];
    const float* Wz_z   = (const float*)d_in[2];
    const float* Wz_r   = (const float*)d_in[3];
    const float* Uz_z   = (const float*)d_in[4];
    const float* Uz_r   = (const float*)d_in[5];
    const float* Wr_z   = (const float*)d_in[6];
    const float* Wr_r   = (const float*)d_in[7];
    const float* Ur_z   = (const float*)d_in[8];
    const float* Ur_r   = (const float*)d_in[9];
    // d_in[10..13] (Wh_z, Wh_r, Uh_z, Uh_r) are dead in the reference
    const float* b_z    = (const float*)d_in[14];
    const float* b_r    = (const float*)d_in[15];
    const float* b_h    = (const float*)d_in[16];
    float* ws  = (float*)d_ws;
    float* out = (float*)d_out;

    fc_kernel<<<dim3(256), dim3(256), 0, stream>>>(
        hidden, hyp_x, Wz_z, Uz_z, Wr_z, Ur_z, Wz_r, Uz_r, Wr_r, Ur_r, ws);
    cell_kernel<<<dim3(64), dim3(256), 0, stream>>>(
        hidden, b_z, b_r, b_h, ws, out);
}

// Round 2
// 107.895 us; speedup vs baseline: 1.5601x; 1.5601x over previous
//
#include <hip/hip_runtime.h>
#include <math.h>

#define EPSF 1e-15f

// ---------------------------------------------------------------------------
// HyperGRU cell, B=H=IN=Cc=256, c=1, fp32.
// _mlr collapses: q[c,b] = tanh(r[b]*|z_c|)*zhat_c, a_unit = zhat_c, so
// px = (-q)(+)x_b lies in span{zhat_c, x_b} -> each _fc = one 256^3 matmul
// Z*X^T + scalar transcendentals. Wh/Uh fc's are dead code in the reference.
//
// R1 lesson: the previous fc_kernel hit the 256-VGPR cap and spilled
// ~2.6KB/thread -> 262 MB of scratch HBM traffic (= the whole runtime).
// This version stages full K=256 tiles once and caps unrolling to keep
// register pressure low.
//
// ws layout (floats):
//   W0..W3 [b][c] 256x256 at mat*65536            (w = sinh(logits), pre-scale)
//   Spart  at 262144 + mat*2048 + ctile*256 + b   (partial sums of w^2 over c)
// ---------------------------------------------------------------------------

__device__ __forceinline__ float wredsum(float v){
    #pragma unroll
    for (int o = 32; o > 0; o >>= 1) v += __shfl_xor(v, o);
    return v;
}
__device__ __forceinline__ void wredsum3(float& a, float& b, float& c){
    #pragma unroll
    for (int o = 32; o > 0; o >>= 1){
        a += __shfl_xor(a, o);
        b += __shfl_xor(b, o);
        c += __shfl_xor(c, o);
    }
}
__device__ __forceinline__ float artanh_f(float x){
    return 0.5f * logf((1.f + x) / (1.f - x));
}

// Given M = <Z_row_c, X_row_b>, nzc=max(|Z_c|,eps), nac = nzc/cosh(r_c)^2,
// rb = r[b], x2b = |x_b|^2: returns w = sinh(logit) of reference _fc.
__device__ __forceinline__ float fc_elem(float M, float nzc, float nac, float rb, float x2b){
    const float maxn = 1.0f - 4e-3f;
    float d = M / nzc;                       // <zhat_c, x_b>
    float tq = tanhf(rb * nzc);              // |q| = |tq|  (expmap0)
    if (fabsf(tq) > maxn) tq = copysignf(maxn, tq);    // _project(q)
    float A   = 1.f - 2.f*tq*d + x2b;
    float den = 1.f - 2.f*tq*d + tq*tq*x2b;
    den = fmaxf(den, EPSF);
    float alpha = -tq * A / den;             // px = alpha*zhat + beta*x
    float beta  = (1.f - tq*tq) / den;
    float dot  = alpha + beta * d;
    float pxn2 = alpha*alpha + 2.f*alpha*beta*d + beta*beta*x2b;
    pxn2 = fmaxf(pxn2, 0.f);
    float n = fmaxf(sqrtf(pxn2), EPSF);
    if (n > maxn){                           // _project(px)
        float s = maxn / n;
        dot *= s;
        pxn2 = maxn * maxn;
    }
    float lam = 2.f / (1.f - pxn2);
    float logit = 2.f * nac * asinhf(dot * lam);
    return sinhf(logit);
}

// One block = one 32x32 tile of one of 4 matmuls M[c,b] = <Z_c, X_b>.
// Full K=256 staged once; unrolls capped to avoid the R1 VGPR spill.
__global__ __launch_bounds__(256) void fc_kernel(
    const float* __restrict__ hidden, const float* __restrict__ hyp_x,
    const float* __restrict__ Wz_z, const float* __restrict__ Uz_z,
    const float* __restrict__ Wr_z, const float* __restrict__ Ur_z,
    const float* __restrict__ Wz_r, const float* __restrict__ Uz_r,
    const float* __restrict__ Wr_r, const float* __restrict__ Ur_r,
    float* __restrict__ ws)
{
    __shared__ float As[32][260];   // stride 260: +4 banks/row, <=2-way on reads
    __shared__ float Bs[32][260];
    __shared__ float nz_s[32], na_s[32], x2_s[32], Sred[32];

    const int bid   = blockIdx.x;
    const int mat   = bid >> 6;         // 0:Wz 1:Uz 2:Wr 3:Ur
    const int tile  = bid & 63;
    const int ctile = tile >> 3;
    const int cbase = ctile * 32;
    const int bbase = (tile & 7) * 32;

    const float* Z  = (mat==0) ? Wz_z : (mat==1) ? Uz_z : (mat==2) ? Wr_z : Ur_z;
    const float* Rv = (mat==0) ? Wz_r : (mat==1) ? Uz_r : (mat==2) ? Wr_r : Ur_r;
    const float* X  = (mat==0 || mat==2) ? hidden : hyp_x;

    const int t  = threadIdx.x;
    const int tc = t >> 4, tb = t & 15;

    // ---- stage both 32x256 tiles (2048 float4 each, 8 per thread) ----
    #pragma unroll 2
    for (int q = 0; q < 8; ++q){
        int f   = q*256 + t;
        int row = f >> 6;           // 64 float4 per row
        int col = (f & 63) * 4;
        *(float4*)&As[row][col] = *(const float4*)(Z + (cbase+row)*256 + col);
        *(float4*)&Bs[row][col] = *(const float4*)(X + (bbase+row)*256 + col);
    }
    __syncthreads();

    // ---- row-norm partials: 8 threads per row, 32 floats each ----
    float sa = 0.f, sb = 0.f;
    {
        int r = t >> 3, seg = t & 7;
        #pragma unroll 2
        for (int q = 0; q < 8; ++q){
            float4 a = *(const float4*)&As[r][seg*32 + q*4];
            float4 b = *(const float4*)&Bs[r][seg*32 + q*4];
            sa += a.x*a.x + a.y*a.y + a.z*a.z + a.w*a.w;
            sb += b.x*b.x + b.y*b.y + b.z*b.z + b.w*b.w;
        }
    }
    sa += __shfl_xor(sa, 1); sb += __shfl_xor(sb, 1);
    sa += __shfl_xor(sa, 2); sb += __shfl_xor(sb, 2);
    sa += __shfl_xor(sa, 4); sb += __shfl_xor(sb, 4);
    if ((t & 7) == 0){
        int r = t >> 3;
        float nzv = fmaxf(sqrtf(sa), EPSF);
        nz_s[r] = nzv;
        float ch = coshf(Rv[cbase + r]);
        na_s[r] = nzv / (ch*ch);
        x2_s[r] = sb;
    }
    if (t < 32) Sred[t] = 0.f;

    // ---- 2x2 micro-tile dot products over K=256 (unroll capped!) ----
    float acc00 = 0.f, acc01 = 0.f, acc10 = 0.f, acc11 = 0.f;
    #pragma unroll 4
    for (int k = 0; k < 256; k += 4){
        float4 a0 = *(const float4*)&As[tc][k];
        float4 a1 = *(const float4*)&As[tc+16][k];
        float4 b0 = *(const float4*)&Bs[tb][k];
        float4 b1 = *(const float4*)&Bs[tb+16][k];
        acc00 += a0.x*b0.x + a0.y*b0.y + a0.z*b0.z + a0.w*b0.w;
        acc01 += a0.x*b1.x + a0.y*b1.y + a0.z*b1.z + a0.w*b1.w;
        acc10 += a1.x*b0.x + a1.y*b0.y + a1.z*b0.z + a1.w*b0.w;
        acc11 += a1.x*b1.x + a1.y*b1.y + a1.z*b1.z + a1.w*b1.w;
    }
    __syncthreads();   // covers nz_s/x2_s/Sred writes above

    const int c0 = cbase + tc, c1 = cbase + tc + 16;
    const int b0 = bbase + tb, b1 = bbase + tb + 16;
    float nz0 = nz_s[tc],   nz1 = nz_s[tc+16];
    float na0 = na_s[tc],   na1 = na_s[tc+16];
    float x20 = x2_s[tb],   x21 = x2_s[tb+16];
    float r0  = Rv[b0],     r1  = Rv[b1];

    float w00 = fc_elem(acc00, nz0, na0, r0, x20);   // -> W[b0][c0]
    float w01 = fc_elem(acc01, nz0, na0, r1, x21);   // -> W[b1][c0]
    float w10 = fc_elem(acc10, nz1, na1, r0, x20);   // -> W[b0][c1]
    float w11 = fc_elem(acc11, nz1, na1, r1, x21);   // -> W[b1][c1]

    float* Wout = ws + mat * 65536;
    Wout[b0*256 + c0] = w00;
    Wout[b1*256 + c0] = w01;
    Wout[b0*256 + c1] = w10;
    Wout[b1*256 + c1] = w11;

    atomicAdd(&Sred[tb],      w00*w00 + w10*w10);
    atomicAdd(&Sred[tb+16],   w01*w01 + w11*w11);
    __syncthreads();
    if (t < 32) ws[262144 + mat*2048 + ctile*256 + bbase + t] = Sred[t];
}

// wave-per-row Mobius add with projection; returns final norm (>= EPSF)
__device__ __forceinline__ float mobius_add4(const float x[4], const float y[4], float res[4]){
    float x2 = 0.f, y2 = 0.f, xy = 0.f;
    #pragma unroll
    for (int k = 0; k < 4; ++k){ x2 += x[k]*x[k]; y2 += y[k]*y[k]; xy += x[k]*y[k]; }
    wredsum3(x2, y2, xy);
    float cA  = 1.f + 2.f*xy + y2;
    float cB  = 1.f - x2;
    float den = fmaxf(1.f + 2.f*xy + x2*y2, EPSF);
    float n2  = 0.f;
    #pragma unroll
    for (int k = 0; k < 4; ++k){ res[k] = (cA*x[k] + cB*y[k]) / den; n2 += res[k]*res[k]; }
    n2 = wredsum(n2);
    float n = fmaxf(sqrtf(n2), EPSF);
    const float maxn = 1.0f - 4e-3f;
    if (n > maxn){
        float s = maxn / n;
        #pragma unroll
        for (int k = 0; k < 4; ++k) res[k] *= s;
        n = maxn;
    }
    return n;
}

// dst[k] = (sqrt(S_m[c]) + 1) * W_m[b][c]   (the _fc scale, indexed by column c)
__device__ __forceinline__ void load_G(const float* __restrict__ ws, int mat, int b, int c4, float dst[4]){
    const float* Wm = ws + mat*65536;
    float4 g = *(const float4*)(Wm + b*256 + c4);
    const float* Sp = ws + 262144 + mat*2048;
    float s0 = 0.f, s1 = 0.f, s2 = 0.f, s3 = 0.f;
    #pragma unroll 2
    for (int ct = 0; ct < 8; ++ct){
        float4 sp = *(const float4*)(Sp + ct*256 + c4);
        s0 += sp.x; s1 += sp.y; s2 += sp.z; s3 += sp.w;
    }
    dst[0] = (sqrtf(s0) + 1.f) * g.x;
    dst[1] = (sqrtf(s1) + 1.f) * g.y;
    dst[2] = (sqrtf(s2) + 1.f) * g.z;
    dst[3] = (sqrtf(s3) + 1.f) * g.w;
}

// One wave per output row b: the whole Mobius/logmap/sigmoid/pw-mul chain.
__global__ __launch_bounds__(256) void cell_kernel(
    const float* __restrict__ hidden,
    const float* __restrict__ b_z, const float* __restrict__ b_r, const float* __restrict__ b_h,
    const float* __restrict__ ws, float* __restrict__ out)
{
    const int b    = blockIdx.x * 4 + (threadIdx.x >> 6);
    const int lane = threadIdx.x & 63;
    const int c4   = lane * 4;
    const float maxn = 1.0f - 4e-3f;

    float h[4], u[4], v[4], t1[4], pre[4], zv[4], rv[4], ht[4], tmp[4], pw[4];

    { float4 hv = *(const float4*)(hidden + b*256 + c4);
      h[0]=hv.x; h[1]=hv.y; h[2]=hv.z; h[3]=hv.w; }

    // ---- z gate: sigmoid(logmap0( (G(h,Wz) (+) G(x,Uz)) (+) b_z )) ----
    load_G(ws, 0, b, c4, u);
    load_G(ws, 1, b, c4, v);
    mobius_add4(u, v, t1);
    { float4 bb = *(const float4*)(b_z + c4); tmp[0]=bb.x; tmp[1]=bb.y; tmp[2]=bb.z; tmp[3]=bb.w; }
    float n  = mobius_add4(t1, tmp, pre);
    float tt = artanh_f(fminf(n, 1.f - 1e-7f));
    float sc = tt / n;
    #pragma unroll
    for (int k = 0; k < 4; ++k) zv[k] = 1.f / (1.f + expf(-pre[k]*sc));

    // ---- r gate ----
    load_G(ws, 2, b, c4, u);
    load_G(ws, 3, b, c4, v);
    mobius_add4(u, v, t1);
    { float4 bb = *(const float4*)(b_r + c4); tmp[0]=bb.x; tmp[1]=bb.y; tmp[2]=bb.z; tmp[3]=bb.w; }
    n  = mobius_add4(t1, tmp, pre);
    tt = artanh_f(fminf(n, 1.f - 1e-7f));
    sc = tt / n;
    #pragma unroll
    for (int k = 0; k < 4; ++k) rv[k] = 1.f / (1.f + expf(-pre[k]*sc));

    // ---- h_tilde = r (+) b_h ----
    { float4 bb = *(const float4*)(b_h + c4); tmp[0]=bb.x; tmp[1]=bb.y; tmp[2]=bb.z; tmp[3]=bb.w; }
    mobius_add4(rv, tmp, ht);

    // ---- mh = (-hidden) (+) h_tilde ----
    #pragma unroll
    for (int k = 0; k < 4; ++k) tmp[k] = -h[k];
    float mh[4];
    mobius_add4(tmp, ht, mh);

    // ---- pw = mobius_pointwise_mul(mh, z) ----
    float xn2 = 0.f, wxn2 = 0.f, dum = 0.f;
    #pragma unroll
    for (int k = 0; k < 4; ++k){ tmp[k] = mh[k]*zv[k]; xn2 += zv[k]*zv[k]; wxn2 += tmp[k]*tmp[k]; }
    wredsum3(xn2, wxn2, dum);
    float xn  = fmaxf(sqrtf(xn2),  EPSF);
    float wxn = fmaxf(sqrtf(wxn2), EPSF);
    float ttp = artanh_f(fminf(xn, 1.f - 1e-7f));
    float th  = tanhf(wxn / xn * ttp);
    float coef = th / wxn;                       // |pw| = th analytically
    if (th > maxn) coef *= maxn / th;            // _project(pw)
    #pragma unroll
    for (int k = 0; k < 4; ++k) pw[k] = coef * tmp[k];

    // ---- out = hidden (+) pw ----
    mobius_add4(h, pw, tmp);
    float4 o; o.x = tmp[0]; o.y = tmp[1]; o.z = tmp[2]; o.w = tmp[3];
    *(float4*)(out + b*256 + c4) = o;
}

extern "C" void kernel_launch(void* const* d_in, const int* in_sizes, int n_in,
                              void* d_out, int out_size, void* d_ws, size_t ws_size,
                              hipStream_t stream) {
    (void)in_sizes; (void)n_in; (void)out_size; (void)ws_size;
    const float* hyp_x  = (const float*)d_in[0];
    const float* hidden = (const float*)d_in[1];
    const float* Wz_z   = (const float*)d_in[2];
    const float* Wz_r   = (const float*)d_in[3];
    const float* Uz_z   = (const float*)d_in[4];
    const float* Uz_r   = (const float*)d_in[5];
    const float* Wr_z   = (const float*)d_in[6];
    const float* Wr_r   = (const float*)d_in[7];
    const float* Ur_z   = (const float*)d_in[8];
    const float* Ur_r   = (const float*)d_in[9];
    // d_in[10..13] (Wh_z, Wh_r, Uh_z, Uh_r) are dead in the reference
    const float* b_z    = (const float*)d_in[14];
    const float* b_r    = (const float*)d_in[15];
    const float* b_h    = (const float*)d_in[16];
    float* ws  = (float*)d_ws;
    float* out = (float*)d_out;

    fc_kernel<<<dim3(256), dim3(256), 0, stream>>>(
        hidden, hyp_x, Wz_z, Uz_z, Wr_z, Ur_z, Wz_r, Uz_r, Wr_r, Ur_r, ws);
    cell_kernel<<<dim3(64), dim3(256), 0, stream>>>(
        hidden, b_z, b_r, b_h, ws, out);
}

// Round 3
// 102.362 us; speedup vs baseline: 1.6445x; 1.0540x over previous
//
#include <hip/hip_runtime.h>
#include <math.h>

#define EPSF 1e-15f

// ---------------------------------------------------------------------------
// HyperGRU cell, B=H=IN=Cc=256, c=1, fp32.
// _mlr collapses: q[c,b] = tanh(r[b]*|z_c|)*zhat_c, a_unit = zhat_c, so
// px = (-q)(+)x_b lies in span{zhat_c, x_b} -> each _fc = one 256^3 matmul
// Z*X^T + scalar transcendentals. Wh/Uh fc's are dead code in the reference.
//
// R1 lesson: 256-VGPR spill (262 MB scratch traffic) from full unroll.
// R2 lesson: harness re-poison of d_ws (268 MB fill, ~40 us) dominates the
//   measurement floor; our kernels must just stay out of the way.
// R3: ocml precise transcendentals (tanhf/sinhf/asinhf/logf/expf) are long,
//   branchy, register-hungry. Replace with v_exp/v_log/v_rcp-based fast
//   versions (~1e-7 rel err; threshold headroom is ~5x).
//
// ws layout (floats):
//   W0..W3 [b][c] 256x256 at mat*65536            (w = sinh(logits), pre-scale)
//   Spart  at 262144 + mat*2048 + ctile*256 + b   (partial sums of w^2 over c)
// ---------------------------------------------------------------------------

// ---- fast transcendentals (v_exp_f32 / v_log_f32 / v_rcp_f32) ----
__device__ __forceinline__ float f_rcp(float x){ return __builtin_amdgcn_rcpf(x); }
__device__ __forceinline__ float f_tanh(float x){
    float e = __expf(2.f * x);              // +inf -> 1, 0 -> -1 : overflow-safe
    return 1.f - 2.f * f_rcp(e + 1.f);
}
__device__ __forceinline__ float f_sinh(float x){
    float e = __expf(x);
    return 0.5f * (e - f_rcp(e));
}
__device__ __forceinline__ float f_cosh(float x){
    float e = __expf(x);
    return 0.5f * (e + f_rcp(e));
}
__device__ __forceinline__ float f_asinh(float x){
    float ax = fabsf(x);
    float r = __logf(ax + sqrtf(fmaf(ax, ax, 1.f)));
    return copysignf(r, x);
}
__device__ __forceinline__ float f_artanh(float x){    // x in [0, 1)
    return 0.5f * __logf((1.f + x) * f_rcp(1.f - x));
}
__device__ __forceinline__ float f_sigmoid(float x){
    return f_rcp(1.f + __expf(-x));
}

__device__ __forceinline__ float wredsum(float v){
    #pragma unroll
    for (int o = 32; o > 0; o >>= 1) v += __shfl_xor(v, o);
    return v;
}
__device__ __forceinline__ void wredsum3(float& a, float& b, float& c){
    #pragma unroll
    for (int o = 32; o > 0; o >>= 1){
        a += __shfl_xor(a, o);
        b += __shfl_xor(b, o);
        c += __shfl_xor(c, o);
    }
}

// Given M = <Z_row_c, X_row_b>, nzc=max(|Z_c|,eps), nac = nzc/cosh(r_c)^2,
// rb = r[b], x2b = |x_b|^2: returns w = sinh(logit) of reference _fc.
__device__ __forceinline__ float fc_elem(float M, float nzc, float nac, float rb, float x2b){
    const float maxn = 1.0f - 4e-3f;
    float d  = M * f_rcp(nzc);               // <zhat_c, x_b>
    float tq = f_tanh(rb * nzc);             // |q| = |tq|  (expmap0)
    if (fabsf(tq) > maxn) tq = copysignf(maxn, tq);    // _project(q)
    float A    = fmaf(-2.f*tq, d, 1.f + x2b);
    float den  = fmaxf(fmaf(tq*tq, x2b, fmaf(-2.f*tq, d, 1.f)), EPSF);
    float rden = f_rcp(den);
    float alpha = -tq * A * rden;            // px = alpha*zhat + beta*x
    float beta  = (1.f - tq*tq) * rden;
    float dot   = fmaf(beta, d, alpha);
    float pxn2  = fmaxf(alpha*alpha + 2.f*alpha*beta*d + beta*beta*x2b, 0.f);
    float n = fmaxf(sqrtf(pxn2), EPSF);
    if (n > maxn){                           // _project(px)
        dot *= maxn * f_rcp(n);
        pxn2 = maxn * maxn;
    }
    float lam = 2.f * f_rcp(1.f - pxn2);
    return f_sinh(2.f * nac * f_asinh(dot * lam));
}

// One block = one 32x32 tile of one of 4 matmuls M[c,b] = <Z_c, X_b>.
__global__ __launch_bounds__(256) void fc_kernel(
    const float* __restrict__ hidden, const float* __restrict__ hyp_x,
    const float* __restrict__ Wz_z, const float* __restrict__ Uz_z,
    const float* __restrict__ Wr_z, const float* __restrict__ Ur_z,
    const float* __restrict__ Wz_r, const float* __restrict__ Uz_r,
    const float* __restrict__ Wr_r, const float* __restrict__ Ur_r,
    float* __restrict__ ws)
{
    __shared__ float As[32][260];   // stride 260: +4 banks/row, <=2-way (free)
    __shared__ float Bs[32][260];
    __shared__ float nz_s[32], na_s[32], x2_s[32], Sred[32];

    const int bid   = blockIdx.x;
    const int mat   = bid >> 6;         // 0:Wz 1:Uz 2:Wr 3:Ur
    const int tile  = bid & 63;
    const int ctile = tile >> 3;
    const int cbase = ctile * 32;
    const int bbase = (tile & 7) * 32;

    const float* Z  = (mat==0) ? Wz_z : (mat==1) ? Uz_z : (mat==2) ? Wr_z : Ur_z;
    const float* Rv = (mat==0) ? Wz_r : (mat==1) ? Uz_r : (mat==2) ? Wr_r : Ur_r;
    const float* X  = (mat==0 || mat==2) ? hidden : hyp_x;

    const int t  = threadIdx.x;
    const int tc = t >> 4, tb = t & 15;

    // ---- stage both 32x256 tiles (2048 float4 each, 8 per thread) ----
    #pragma unroll 4
    for (int q = 0; q < 8; ++q){
        int f   = q*256 + t;
        int row = f >> 6;           // 64 float4 per row
        int col = (f & 63) * 4;
        *(float4*)&As[row][col] = *(const float4*)(Z + (cbase+row)*256 + col);
        *(float4*)&Bs[row][col] = *(const float4*)(X + (bbase+row)*256 + col);
    }
    __syncthreads();

    // ---- row-norm partials: 8 threads per row, 32 floats each ----
    float sa = 0.f, sb = 0.f;
    {
        int r = t >> 3, seg = t & 7;
        #pragma unroll 2
        for (int q = 0; q < 8; ++q){
            float4 a = *(const float4*)&As[r][seg*32 + q*4];
            float4 b = *(const float4*)&Bs[r][seg*32 + q*4];
            sa += a.x*a.x + a.y*a.y + a.z*a.z + a.w*a.w;
            sb += b.x*b.x + b.y*b.y + b.z*b.z + b.w*b.w;
        }
    }
    sa += __shfl_xor(sa, 1); sb += __shfl_xor(sb, 1);
    sa += __shfl_xor(sa, 2); sb += __shfl_xor(sb, 2);
    sa += __shfl_xor(sa, 4); sb += __shfl_xor(sb, 4);
    if ((t & 7) == 0){
        int r = t >> 3;
        float nzv = fmaxf(sqrtf(sa), EPSF);
        nz_s[r] = nzv;
        float ch = f_cosh(Rv[cbase + r]);
        na_s[r] = nzv * f_rcp(ch*ch);
        x2_s[r] = sb;
    }
    if (t < 32) Sred[t] = 0.f;

    // ---- 2x2 micro-tile dot products over K=256 (unroll capped!) ----
    float acc00 = 0.f, acc01 = 0.f, acc10 = 0.f, acc11 = 0.f;
    #pragma unroll 4
    for (int k = 0; k < 256; k += 4){
        float4 a0 = *(const float4*)&As[tc][k];
        float4 a1 = *(const float4*)&As[tc+16][k];
        float4 b0 = *(const float4*)&Bs[tb][k];
        float4 b1 = *(const float4*)&Bs[tb+16][k];
        acc00 += a0.x*b0.x + a0.y*b0.y + a0.z*b0.z + a0.w*b0.w;
        acc01 += a0.x*b1.x + a0.y*b1.y + a0.z*b1.z + a0.w*b1.w;
        acc10 += a1.x*b0.x + a1.y*b0.y + a1.z*b0.z + a1.w*b0.w;
        acc11 += a1.x*b1.x + a1.y*b1.y + a1.z*b1.z + a1.w*b1.w;
    }
    __syncthreads();   // covers nz_s/x2_s/Sred writes above

    const int c0 = cbase + tc, c1 = cbase + tc + 16;
    const int b0 = bbase + tb, b1 = bbase + tb + 16;
    float nz0 = nz_s[tc],   nz1 = nz_s[tc+16];
    float na0 = na_s[tc],   na1 = na_s[tc+16];
    float x20 = x2_s[tb],   x21 = x2_s[tb+16];
    float r0  = Rv[b0],     r1  = Rv[b1];

    float w00 = fc_elem(acc00, nz0, na0, r0, x20);   // -> W[b0][c0]
    float w01 = fc_elem(acc01, nz0, na0, r1, x21);   // -> W[b1][c0]
    float w10 = fc_elem(acc10, nz1, na1, r0, x20);   // -> W[b0][c1]
    float w11 = fc_elem(acc11, nz1, na1, r1, x21);   // -> W[b1][c1]

    float* Wout = ws + mat * 65536;
    Wout[b0*256 + c0] = w00;
    Wout[b1*256 + c0] = w01;
    Wout[b0*256 + c1] = w10;
    Wout[b1*256 + c1] = w11;

    atomicAdd(&Sred[tb],      w00*w00 + w10*w10);
    atomicAdd(&Sred[tb+16],   w01*w01 + w11*w11);
    __syncthreads();
    if (t < 32) ws[262144 + mat*2048 + ctile*256 + bbase + t] = Sred[t];
}

// wave-per-row Mobius add with projection; returns final norm (>= EPSF)
__device__ __forceinline__ float mobius_add4(const float x[4], const float y[4], float res[4]){
    float x2 = 0.f, y2 = 0.f, xy = 0.f;
    #pragma unroll
    for (int k = 0; k < 4; ++k){ x2 += x[k]*x[k]; y2 += y[k]*y[k]; xy += x[k]*y[k]; }
    wredsum3(x2, y2, xy);
    float cA  = 1.f + 2.f*xy + y2;
    float cB  = 1.f - x2;
    float rden = f_rcp(fmaxf(1.f + 2.f*xy + x2*y2, EPSF));
    float n2  = 0.f;
    #pragma unroll
    for (int k = 0; k < 4; ++k){ res[k] = (cA*x[k] + cB*y[k]) * rden; n2 += res[k]*res[k]; }
    n2 = wredsum(n2);
    float n = fmaxf(sqrtf(n2), EPSF);
    const float maxn = 1.0f - 4e-3f;
    if (n > maxn){
        float s = maxn * f_rcp(n);
        #pragma unroll
        for (int k = 0; k < 4; ++k) res[k] *= s;
        n = maxn;
    }
    return n;
}

// dst[k] = (sqrt(S_m[c]) + 1) * W_m[b][c]   (the _fc scale, indexed by column c)
__device__ __forceinline__ void load_G(const float* __restrict__ ws, int mat, int b, int c4, float dst[4]){
    const float* Wm = ws + mat*65536;
    float4 g = *(const float4*)(Wm + b*256 + c4);
    const float* Sp = ws + 262144 + mat*2048;
    float s0 = 0.f, s1 = 0.f, s2 = 0.f, s3 = 0.f;
    #pragma unroll 2
    for (int ct = 0; ct < 8; ++ct){
        float4 sp = *(const float4*)(Sp + ct*256 + c4);
        s0 += sp.x; s1 += sp.y; s2 += sp.z; s3 += sp.w;
    }
    dst[0] = (sqrtf(s0) + 1.f) * g.x;
    dst[1] = (sqrtf(s1) + 1.f) * g.y;
    dst[2] = (sqrtf(s2) + 1.f) * g.z;
    dst[3] = (sqrtf(s3) + 1.f) * g.w;
}

// One wave per output row b: the whole Mobius/logmap/sigmoid/pw-mul chain.
__global__ __launch_bounds__(256) void cell_kernel(
    const float* __restrict__ hidden,
    const float* __restrict__ b_z, const float* __restrict__ b_r, const float* __restrict__ b_h,
    const float* __restrict__ ws, float* __restrict__ out)
{
    const int b    = blockIdx.x * 4 + (threadIdx.x >> 6);
    const int lane = threadIdx.x & 63;
    const int c4   = lane * 4;
    const float maxn = 1.0f - 4e-3f;

    float h[4], u[4], v[4], t1[4], pre[4], zv[4], rv[4], ht[4], tmp[4], pw[4], mh[4];

    { float4 hv = *(const float4*)(hidden + b*256 + c4);
      h[0]=hv.x; h[1]=hv.y; h[2]=hv.z; h[3]=hv.w; }

    // ---- z gate: sigmoid(logmap0( (G(h,Wz) (+) G(x,Uz)) (+) b_z )) ----
    load_G(ws, 0, b, c4, u);
    load_G(ws, 1, b, c4, v);
    mobius_add4(u, v, t1);
    { float4 bb = *(const float4*)(b_z + c4); tmp[0]=bb.x; tmp[1]=bb.y; tmp[2]=bb.z; tmp[3]=bb.w; }
    float n  = mobius_add4(t1, tmp, pre);
    float sc = f_artanh(fminf(n, 1.f - 1e-7f)) * f_rcp(n);
    #pragma unroll
    for (int k = 0; k < 4; ++k) zv[k] = f_sigmoid(pre[k]*sc);

    // ---- r gate ----
    load_G(ws, 2, b, c4, u);
    load_G(ws, 3, b, c4, v);
    mobius_add4(u, v, t1);
    { float4 bb = *(const float4*)(b_r + c4); tmp[0]=bb.x; tmp[1]=bb.y; tmp[2]=bb.z; tmp[3]=bb.w; }
    n  = mobius_add4(t1, tmp, pre);
    sc = f_artanh(fminf(n, 1.f - 1e-7f)) * f_rcp(n);
    #pragma unroll
    for (int k = 0; k < 4; ++k) rv[k] = f_sigmoid(pre[k]*sc);

    // ---- h_tilde = r (+) b_h ----
    { float4 bb = *(const float4*)(b_h + c4); tmp[0]=bb.x; tmp[1]=bb.y; tmp[2]=bb.z; tmp[3]=bb.w; }
    mobius_add4(rv, tmp, ht);

    // ---- mh = (-hidden) (+) h_tilde ----
    #pragma unroll
    for (int k = 0; k < 4; ++k) tmp[k] = -h[k];
    mobius_add4(tmp, ht, mh);

    // ---- pw = mobius_pointwise_mul(mh, z) ----
    float xn2 = 0.f, wxn2 = 0.f, dum = 0.f;
    #pragma unroll
    for (int k = 0; k < 4; ++k){ tmp[k] = mh[k]*zv[k]; xn2 += zv[k]*zv[k]; wxn2 += tmp[k]*tmp[k]; }
    wredsum3(xn2, wxn2, dum);
    float xn  = fmaxf(sqrtf(xn2),  EPSF);
    float wxn = fmaxf(sqrtf(wxn2), EPSF);
    float th  = f_tanh(wxn * f_rcp(xn) * f_artanh(fminf(xn, 1.f - 1e-7f)));
    float coef = th * f_rcp(wxn);                // |pw| = th analytically
    if (th > maxn) coef *= maxn * f_rcp(th);     // _project(pw)
    #pragma unroll
    for (int k = 0; k < 4; ++k) pw[k] = coef * tmp[k];

    // ---- out = hidden (+) pw ----
    mobius_add4(h, pw, tmp);
    float4 o; o.x = tmp[0]; o.y = tmp[1]; o.z = tmp[2]; o.w = tmp[3];
    *(float4*)(out + b*256 + c4) = o;
}

extern "C" void kernel_launch(void* const* d_in, const int* in_sizes, int n_in,
                              void* d_out, int out_size, void* d_ws, size_t ws_size,
                              hipStream_t stream) {
    (void)in_sizes; (void)n_in; (void)out_size; (void)ws_size;
    const float* hyp_x  = (const float*)d_in[0];
    const float* hidden = (const float*)d_in[1];
    const float* Wz_z   = (const float*)d_in[2];
    const float* Wz_r   = (const float*)d_in[3];
    const float* Uz_z   = (const float*)d_in[4];
    const float* Uz_r   = (const float*)d_in[5];
    const float* Wr_z   = (const float*)d_in[6];
    const float* Wr_r   = (const float*)d_in[7];
    const float* Ur_z   = (const float*)d_in[8];
    const float* Ur_r   = (const float*)d_in[9];
    // d_in[10..13] (Wh_z, Wh_r, Uh_z, Uh_r) are dead in the reference
    const float* b_z    = (const float*)d_in[14];
    const float* b_r    = (const float*)d_in[15];
    const float* b_h    = (const float*)d_in[16];
    float* ws  = (float*)d_ws;
    float* out = (float*)d_out;

    fc_kernel<<<dim3(256), dim3(256), 0, stream>>>(
        hidden, hyp_x, Wz_z, Uz_z, Wr_z, Ur_z, Wz_r, Uz_r, Wr_r, Ur_r, ws);
    cell_kernel<<<dim3(64), dim3(256), 0, stream>>>(
        hidden, b_z, b_r, b_h, ws, out);
}